// Round 9
// baseline (411.664 us; speedup 1.0000x reference)
//
#include <hip/hip_runtime.h>
#include <hip/hip_cooperative_groups.h>

namespace cg = cooperative_groups;

#define S_LEN 2048
#define BATCH 4
#define DMODEL 512
#define NHEAD 8
#define HDIM 64
#define ROWS (BATCH * S_LEN) /* 8192 */

using short8 = __attribute__((ext_vector_type(8))) short;
using f32x4  = __attribute__((ext_vector_type(4))) float;

__device__ __forceinline__ unsigned short f2bf(float f) {
  unsigned int u = __builtin_bit_cast(unsigned int, f);
  u += 0x7fffu + ((u >> 16) & 1u);
  return (unsigned short)(u >> 16);
}
__device__ __forceinline__ float bf2f(unsigned short h) {
  unsigned int u = ((unsigned int)h) << 16;
  return __builtin_bit_cast(float, u);
}
__device__ __forceinline__ void glds16(const void* g, void* l) {
  __builtin_amdgcn_global_load_lds((const __attribute__((address_space(1))) unsigned*)g,
                                   (__attribute__((address_space(3))) unsigned*)l, 16, 0, 0);
}

struct MegaArgs {
  const float *x, *Wq, *bq, *Wk, *bk, *Wv, *bv, *Wo, *bo;
  const int* x_len;
  float* out;
  unsigned short *xb, *Qb, *Kb, *Vt, *WqkT, *WvT, *WoT, *Cx;
  float *vsum, *trow;
};

// ---------------- phase bodies (shared by mega + fallback kernels) ----------------

__device__ void phase_prep_unit(const MegaArgs& a, int unit, char* smem) {
  const int tid = threadIdx.x;
  if (unit < 2048) {
    const int base = (unit * 256 + tid) * 8;
    float4 f0 = *(const float4*)(a.x + base);
    float4 f1 = *(const float4*)(a.x + base + 4);
    uint4 o;
    o.x = (unsigned)f2bf(f0.x) | ((unsigned)f2bf(f0.y) << 16);
    o.y = (unsigned)f2bf(f0.z) | ((unsigned)f2bf(f0.w) << 16);
    o.z = (unsigned)f2bf(f1.x) | ((unsigned)f2bf(f1.y) << 16);
    o.w = (unsigned)f2bf(f1.z) | ((unsigned)f2bf(f1.w) << 16);
    *(uint4*)(a.xb + base) = o;
  } else {
    float (*t)[33] = (float(*)[33])smem;
    const int tb = unit - 2048;
    const int which = tb >> 8, tile = tb & 255;
    const float* W = which == 0 ? a.Wq : which == 1 ? a.Wk : which == 2 ? a.Wv : a.Wo;
    unsigned short* WT = which == 0 ? a.WqkT : which == 1 ? (a.WqkT + 512 * 512)
                        : which == 2 ? a.WvT : a.WoT;
    const int tx = tid & 31, ty = tid >> 5;
    const int x0 = (tile & 15) * 32, y0 = (tile >> 4) * 32;
    __syncthreads(); // protect previous unit's t reads (mega loop reuse)
#pragma unroll
    for (int r = 0; r < 4; r++)
      t[ty + 8 * r][tx] = W[(size_t)(y0 + ty + 8 * r) * DMODEL + x0 + tx];
    __syncthreads();
#pragma unroll
    for (int r = 0; r < 4; r++)
      WT[(size_t)(x0 + ty + 8 * r) * DMODEL + y0 + tx] = f2bf(t[tx][ty + 8 * r]);
  }
}

__device__ void phase_qkv_unit(const MegaArgs& a, int unit, char* smem) {
  const int tid = threadIdx.x;
  const bool vmode = unit < 256;
  const unsigned short *A, *Bt;
  int m0, n0;
  if (vmode) {
    m0 = (unit & 3) * 128;   // feature
    n0 = (unit >> 2) * 128;  // row
    A = a.WvT; Bt = a.xb;
  } else {
    const int q = unit - 256;
    m0 = (q >> 3) * 128;     // row
    n0 = (q & 7) * 128;      // col (0-511 Q, 512-1023 K)
    A = a.xb; Bt = a.WqkT;
    const int xl = a.x_len[m0 >> 11];
    const int s0 = m0 & 2047;
    if (n0 >= DMODEL) { if (s0 >= xl) return; }   // K rows >= xlen unobserved
    else if (s0 >= xl + 128) return;              // Q rows >= xlen+128 unobserved
  }
  char* As = smem;
  char* Bs = smem + 8192;
  const int wave = tid >> 6, lane = tid & 63;
  const int wr = wave >> 1, wc = wave & 1;
  const int lm = lane & 15, lq = lane >> 4;
  const int lr = lane >> 2;
  const int lc = (lane & 3) ^ ((lane >> 3) & 3);
  const unsigned short* gA0 = A + (size_t)(m0 + wave * 16 + lr) * DMODEL + lc * 8;
  const unsigned short* gA1 = A + (size_t)(m0 + (wave + 4) * 16 + lr) * DMODEL + lc * 8;
  const unsigned short* gB0 = Bt + (size_t)(n0 + wave * 16 + lr) * DMODEL + lc * 8;
  const unsigned short* gB1 = Bt + (size_t)(n0 + (wave + 4) * 16 + lr) * DMODEL + lc * 8;
  char* lA0 = As + wave * 1024 + lane * 16;
  char* lA1 = As + (wave + 4) * 1024 + lane * 16;
  char* lB0 = Bs + wave * 1024 + lane * 16;
  char* lB1 = Bs + (wave + 4) * 1024 + lane * 16;
  const int sw = (lm >> 1) & 3;
  int aoff[4], boff[4];
#pragma unroll
  for (int mi = 0; mi < 4; mi++) aoff[mi] = (wr * 64 + mi * 16 + lm) * 64 + (lq ^ sw) * 16;
#pragma unroll
  for (int ni = 0; ni < 4; ni++) boff[ni] = (wc * 64 + ni * 16 + lm) * 64 + (lq ^ sw) * 16;
  f32x4 acc[4][4] = {};
  for (int k0 = 0; k0 < DMODEL; k0 += 32) {
    __syncthreads();
    glds16(gA0 + k0, lA0);
    glds16(gA1 + k0, lA1);
    glds16(gB0 + k0, lB0);
    glds16(gB1 + k0, lB1);
    __syncthreads();
    short8 af[4], bfr[4];
#pragma unroll
    for (int mi = 0; mi < 4; mi++) af[mi] = *(const short8*)(As + aoff[mi]);
#pragma unroll
    for (int ni = 0; ni < 4; ni++) bfr[ni] = *(const short8*)(Bs + boff[ni]);
#pragma unroll
    for (int mi = 0; mi < 4; mi++)
#pragma unroll
      for (int ni = 0; ni < 4; ni++)
        acc[mi][ni] = __builtin_amdgcn_mfma_f32_16x16x32_bf16(af[mi], bfr[ni], acc[mi][ni], 0, 0, 0);
  }
#pragma unroll
  for (int mi = 0; mi < 4; mi++) {
    const int row0 = m0 + wr * 64 + mi * 16 + lq * 4;
#pragma unroll
    for (int ni = 0; ni < 4; ni++) {
      const int col = n0 + wc * 64 + ni * 16 + lm;
#pragma unroll
      for (int r = 0; r < 4; r++) {
        const int row = row0 + r;
        const float v = acc[mi][ni][r];
        if (vmode) {
          a.Vt[(size_t)row * ROWS + col] = f2bf(v + a.bv[row]);
        } else if (col < DMODEL) {
          a.Qb[(size_t)row * DMODEL + col] = f2bf(v + a.bq[col]);
        } else {
          a.Kb[(size_t)row * DMODEL + (col - DMODEL)] = f2bf(v + a.bk[col - DMODEL]);
        }
      }
    }
  }
}

__device__ void phase_vsum_unit(const MegaArgs& a, int wid) {
  const int lane = threadIdx.x & 63;
  const int b = wid >> 9, n = wid & 511;
  const unsigned short* row = a.Vt + (size_t)n * ROWS + b * S_LEN;
  float s = 0.f;
#pragma unroll
  for (int it = 0; it < 4; it++) {
    uint4 v = *(const uint4*)(row + it * 512 + lane * 8);
    unsigned int w[4] = {v.x, v.y, v.z, v.w};
#pragma unroll
    for (int e = 0; e < 4; e++) {
      s += bf2f((unsigned short)(w[e] & 0xffffu));
      s += bf2f((unsigned short)(w[e] >> 16));
    }
  }
#pragma unroll
  for (int off = 1; off < 64; off <<= 1) s += __shfl_xor(s, off, 64);
  if (lane == 0) a.vsum[(size_t)b * DMODEL + n] = s;
}

__device__ void phase_attn_unit(const MegaArgs& a, int unit, char* smem) {
  const int tid = threadIdx.x;
  if (unit < 1024) {
    const int b = unit >> 8, h = (unit >> 5) & 7;
    const int i0 = (unit & 31) * 64;
    const int xlen = a.x_len[b];
    const int t0 = min(S_LEN, xlen + 128);
    if ((i0 & ~127) >= t0) return; // tail slab: phase 5 broadcasts it
    unsigned short (*Ks)[72] = (unsigned short(*)[72])smem;                  // 4608 B
    unsigned short (*Vs)[40] = (unsigned short(*)[40])(smem + 4608);         // 5120 B
    unsigned short (*Ps)[16][40] = (unsigned short(*)[16][40])(smem + 9728); // 5120 B
    const int wave = tid >> 6, lane = tid & 63;
    const int lm = lane & 15, lq = lane >> 4;
    const int q0 = i0 + wave * 16;
    const size_t qoff = (size_t)(b * S_LEN + q0 + lm) * DMODEL + h * HDIM + lq * 8;
    const short8 aq0 = *(const short8*)(a.Qb + qoff);
    const short8 aq1 = *(const short8*)(a.Qb + qoff + 32);
    const int krow = tid >> 3, kchk = (tid & 7) * 8;
    const int vdim = tid >> 2, vchk = (tid & 3) * 8;
    f32x4 oacc[4] = {};
    float lrow[4] = {0.f, 0.f, 0.f, 0.f};
    for (int kt = 0; kt < 10; kt++) {
      const int jt0 = i0 - 128 + kt * 32;
      if (jt0 + 31 < 0 || jt0 >= xlen) continue;
      __syncthreads();
      {
        const int jr = jt0 + krow;
        const int jrc = min(max(jr, 0), S_LEN - 1);
        *(uint4*)&Ks[krow][kchk] =
            *(const uint4*)(a.Kb + (size_t)(b * S_LEN + jrc) * DMODEL + h * HDIM + kchk);
        const int jv = jt0 + vchk;
        const int jvc = min(max(jv, 0), S_LEN - 8);
        *(uint4*)&Vs[vdim][vchk] =
            *(const uint4*)(a.Vt + (size_t)(h * HDIM + vdim) * ROWS + b * S_LEN + jvc);
      }
      __syncthreads();
      if (jt0 + 31 < q0 - 128 || jt0 > q0 + 143) continue;
      f32x4 sv[2];
#pragma unroll
      for (int sub = 0; sub < 2; sub++) {
        const short8 bk0 = *(const short8*)&Ks[sub * 16 + lm][lq * 8];
        const short8 bk1 = *(const short8*)&Ks[sub * 16 + lm][32 + lq * 8];
        f32x4 s = {};
        s = __builtin_amdgcn_mfma_f32_16x16x32_bf16(aq0, bk0, s, 0, 0, 0);
        s = __builtin_amdgcn_mfma_f32_16x16x32_bf16(aq1, bk1, s, 0, 0, 0);
        sv[sub] = s;
      }
      float p[2][4];
#pragma unroll
      for (int sub = 0; sub < 2; sub++) {
        const int j = jt0 + sub * 16 + lm;
        const bool jv = (j >= 0) && (j < xlen);
#pragma unroll
        for (int r = 0; r < 4; r++) {
          const int i = q0 + lq * 4 + r;
          const bool ok = jv && (j - i <= 128) && (i - j <= 128);
          const float pv = ok ? __expf(sv[sub][r] * 0.125f) : 0.f;
          p[sub][r] = pv;
          lrow[r] += pv;
        }
      }
#pragma unroll
      for (int r = 0; r < 4; r++) {
        Ps[wave][lq * 4 + r][lm] = f2bf(p[0][r]);
        Ps[wave][lq * 4 + r][16 + lm] = f2bf(p[1][r]);
      }
      const short8 pf = *(const short8*)&Ps[wave][lm][lq * 8];
#pragma unroll
      for (int dt = 0; dt < 4; dt++) {
        const short8 bv = *(const short8*)&Vs[dt * 16 + lm][lq * 8];
        oacc[dt] = __builtin_amdgcn_mfma_f32_16x16x32_bf16(pf, bv, oacc[dt], 0, 0, 0);
      }
    }
#pragma unroll
    for (int r = 0; r < 4; r++)
#pragma unroll
      for (int off = 1; off < 16; off <<= 1) lrow[r] += __shfl_xor(lrow[r], off, 64);
#pragma unroll
    for (int r = 0; r < 4; r++) {
      const int i = q0 + lq * 4 + r;
      const size_t obase = (size_t)(b * S_LEN + i) * DMODEL + h * HDIM;
      if (lrow[r] > 0.f) {
        const float inv = 1.f / lrow[r];
#pragma unroll
        for (int dt = 0; dt < 4; dt++)
          a.Cx[obase + dt * 16 + lm] = f2bf(oacc[dt][r] * inv);
      } else {
#pragma unroll
        for (int dt = 0; dt < 4; dt++)
          a.Cx[obase + dt * 16 + lm] =
              f2bf(a.vsum[(size_t)b * DMODEL + h * HDIM + dt * 16 + lm] * (1.f / 2048.f));
      }
    }
  } else {
    // tailrow: trow[b][c] = bo[c] + (vsum[b]/2048) . WoT[c]
    const int u = unit - 1024;
    const int b = u >> 4;
    const int wave = tid >> 6, lane = tid & 63;
    const float* vs = a.vsum + b * DMODEL + lane * 8;
    float vreg[8];
    *(float4*)vreg = *(const float4*)vs;
    *(float4*)(vreg + 4) = *(const float4*)(vs + 4);
#pragma unroll
    for (int ci = 0; ci < 8; ci++) {
      const int c = (u & 15) * 32 + wave * 8 + ci;
      const uint4 wv = *(const uint4*)(a.WoT + (size_t)c * DMODEL + lane * 8);
      const unsigned int w[4] = {wv.x, wv.y, wv.z, wv.w};
      float acc = 0.f;
#pragma unroll
      for (int e = 0; e < 4; e++) {
        acc += vreg[2 * e] * bf2f((unsigned short)(w[e] & 0xffffu));
        acc += vreg[2 * e + 1] * bf2f((unsigned short)(w[e] >> 16));
      }
#pragma unroll
      for (int off = 1; off < 64; off <<= 1) acc += __shfl_xor(acc, off, 64);
      if (lane == 0) a.trow[b * DMODEL + c] = a.bo[c] + acc * (1.f / 2048.f);
    }
  }
}

__device__ void phase_out_unit(const MegaArgs& a, int unit, char* smem) {
  const int tid = threadIdx.x;
  const int m0 = (unit >> 2) * 128, n0 = (unit & 3) * 128;
  const int xl = a.x_len[m0 >> 11];
  if ((m0 & 2047) >= min(S_LEN, xl + 128)) {
    // whole slab is tail: broadcast trow (batch-uniform rows)
    const float4 val = *(const float4*)(a.trow + (m0 >> 11) * DMODEL + n0 + (tid & 31) * 4);
    float* obase = a.out + (size_t)m0 * DMODEL + n0 + (tid & 31) * 4;
#pragma unroll
    for (int r = tid >> 5; r < 128; r += 8)
      *(float4*)(obase + (size_t)r * DMODEL) = val;
    return;
  }
  char* As = smem;
  char* Bs = smem + 8192;
  const int wave = tid >> 6, lane = tid & 63;
  const int wr = wave >> 1, wc = wave & 1;
  const int lm = lane & 15, lq = lane >> 4;
  const int lr = lane >> 2;
  const int lc = (lane & 3) ^ ((lane >> 3) & 3);
  const unsigned short* gA0 = a.Cx + (size_t)(m0 + wave * 16 + lr) * DMODEL + lc * 8;
  const unsigned short* gA1 = a.Cx + (size_t)(m0 + (wave + 4) * 16 + lr) * DMODEL + lc * 8;
  const unsigned short* gB0 = a.WoT + (size_t)(n0 + wave * 16 + lr) * DMODEL + lc * 8;
  const unsigned short* gB1 = a.WoT + (size_t)(n0 + (wave + 4) * 16 + lr) * DMODEL + lc * 8;
  char* lA0 = As + wave * 1024 + lane * 16;
  char* lA1 = As + (wave + 4) * 1024 + lane * 16;
  char* lB0 = Bs + wave * 1024 + lane * 16;
  char* lB1 = Bs + (wave + 4) * 1024 + lane * 16;
  const int sw = (lm >> 1) & 3;
  int aoff[4], boff[4];
#pragma unroll
  for (int mi = 0; mi < 4; mi++) aoff[mi] = (wr * 64 + mi * 16 + lm) * 64 + (lq ^ sw) * 16;
#pragma unroll
  for (int ni = 0; ni < 4; ni++) boff[ni] = (wc * 64 + ni * 16 + lm) * 64 + (lq ^ sw) * 16;
  f32x4 acc[4][4] = {};
  for (int k0 = 0; k0 < DMODEL; k0 += 32) {
    __syncthreads();
    glds16(gA0 + k0, lA0);
    glds16(gA1 + k0, lA1);
    glds16(gB0 + k0, lB0);
    glds16(gB1 + k0, lB1);
    __syncthreads();
    short8 af[4], bfr[4];
#pragma unroll
    for (int mi = 0; mi < 4; mi++) af[mi] = *(const short8*)(As + aoff[mi]);
#pragma unroll
    for (int ni = 0; ni < 4; ni++) bfr[ni] = *(const short8*)(Bs + boff[ni]);
#pragma unroll
    for (int mi = 0; mi < 4; mi++)
#pragma unroll
      for (int ni = 0; ni < 4; ni++)
        acc[mi][ni] = __builtin_amdgcn_mfma_f32_16x16x32_bf16(af[mi], bfr[ni], acc[mi][ni], 0, 0, 0);
  }
#pragma unroll
  for (int mi = 0; mi < 4; mi++) {
    const int row0 = m0 + wr * 64 + mi * 16 + lq * 4;
#pragma unroll
    for (int ni = 0; ni < 4; ni++) {
      const int col = n0 + wc * 64 + ni * 16 + lm;
#pragma unroll
      for (int r = 0; r < 4; r++)
        a.out[(size_t)(row0 + r) * DMODEL + col] = acc[mi][ni][r] + a.bo[col];
    }
  }
}

// ---------------- cooperative mega kernel (grid-stride, any grid size) ------------
__global__ __launch_bounds__(256, 2) void mega_kernel(MegaArgs a) {
  __shared__ __align__(16) char smem[16384];
  const int nb = gridDim.x;
  cg::grid_group grid = cg::this_grid();
  for (int unit = blockIdx.x; unit < 3072; unit += nb) phase_prep_unit(a, unit, smem);
  __threadfence();
  grid.sync();
  for (int unit = blockIdx.x; unit < 768; unit += nb) phase_qkv_unit(a, unit, smem);
  __threadfence();
  grid.sync();
  for (int wid = blockIdx.x * 4 + (threadIdx.x >> 6); wid < 2048; wid += nb * 4)
    phase_vsum_unit(a, wid);
  __threadfence();
  grid.sync();
  for (int unit = blockIdx.x; unit < 1088; unit += nb) phase_attn_unit(a, unit, smem);
  __threadfence();
  grid.sync();
  for (int unit = blockIdx.x; unit < 256; unit += nb) phase_out_unit(a, unit, smem);
}

// ---------------- fallback kernels (one unit per block; R7-equivalent) ------------
__global__ __launch_bounds__(256, 2) void fb_prep(MegaArgs a) {
  __shared__ __align__(16) char smem[16384];
  phase_prep_unit(a, blockIdx.x, smem);
}
__global__ __launch_bounds__(256, 2) void fb_qkv(MegaArgs a) {
  __shared__ __align__(16) char smem[16384];
  phase_qkv_unit(a, blockIdx.x, smem);
}
__global__ __launch_bounds__(256) void fb_vsum(MegaArgs a) {
  phase_vsum_unit(a, blockIdx.x * 4 + (threadIdx.x >> 6));
}
__global__ __launch_bounds__(256) void fb_attn(MegaArgs a) {
  __shared__ __align__(16) char smem[16384];
  phase_attn_unit(a, blockIdx.x, smem);
}
__global__ __launch_bounds__(256, 2) void fb_out(MegaArgs a) {
  __shared__ __align__(16) char smem[16384];
  phase_out_unit(a, blockIdx.x, smem);
}

extern "C" void kernel_launch(void* const* d_in, const int* in_sizes, int n_in,
                              void* d_out, int out_size, void* d_ws, size_t ws_size,
                              hipStream_t stream) {
  (void)in_sizes; (void)n_in; (void)out_size; (void)ws_size;
  char* ws = (char*)d_ws;
  const size_t MB = 1024 * 1024;
  MegaArgs args;
  args.x  = (const float*)d_in[0];
  args.Wq = (const float*)d_in[1];
  args.bq = (const float*)d_in[2];
  args.Wk = (const float*)d_in[3];
  args.bk = (const float*)d_in[4];
  args.Wv = (const float*)d_in[5];
  args.bv = (const float*)d_in[6];
  args.Wo = (const float*)d_in[7];
  args.bo = (const float*)d_in[8];
  args.x_len = (const int*)d_in[9];
  args.out = (float*)d_out;
  args.xb   = (unsigned short*)(ws + 0 * MB);           // [8192][512]
  args.Qb   = (unsigned short*)(ws + 8 * MB);           // [8192][512]
  args.Kb   = (unsigned short*)(ws + 16 * MB);          // [8192][512]
  args.Vt   = (unsigned short*)(ws + 24 * MB);          // [512][8192]
  args.Cx   = (unsigned short*)(ws + 32 * MB);          // [8192][512]
  args.WqkT = (unsigned short*)(ws + 40 * MB);          // [1024][512]
  args.WvT  = (unsigned short*)(ws + 41 * MB);          // [512][512]
  args.WoT  = (unsigned short*)(ws + 41 * MB + 512 * 1024);
  args.vsum = (float*)(ws + 42 * MB);                   // [4][512]
  args.trow = (float*)(ws + 42 * MB + 8192);            // [4][512]

  // host-side occupancy query (capture-safe): clamp cooperative grid to capacity
  int maxBlk = 0;
  hipError_t oe = hipOccupancyMaxActiveBlocksPerMultiprocessor(
      &maxBlk, (const void*)mega_kernel, 256, 0);
  hipError_t le = hipErrorUnknown;
  if (oe == hipSuccess && maxBlk >= 1) {
    const int grid = maxBlk >= 2 ? 512 : 256;
    void* kargs[] = {&args};
    le = hipLaunchCooperativeKernel((const void*)mega_kernel, dim3(grid), dim3(256),
                                    kargs, 0, stream);
  }
  if (le != hipSuccess) {
    // fallback: identical phase bodies as 5 ordered dispatches (R7-equivalent)
    fb_prep<<<3072, 256, 0, stream>>>(args);
    fb_qkv<<<768, 256, 0, stream>>>(args);
    fb_vsum<<<512, 256, 0, stream>>>(args);
    fb_attn<<<1088, 256, 0, stream>>>(args);
    fb_out<<<256, 256, 0, stream>>>(args);
  }
}

// Round 10
// 150.139 us; speedup vs baseline: 2.7419x; 2.7419x over previous
//
#include <hip/hip_runtime.h>

#define S_LEN 2048
#define BATCH 4
#define DMODEL 512
#define NHEAD 8
#define HDIM 64
#define ROWS (BATCH * S_LEN) /* 8192 */

using short8 = __attribute__((ext_vector_type(8))) short;
using f32x4  = __attribute__((ext_vector_type(4))) float;

__device__ __forceinline__ unsigned short f2bf(float f) {
  unsigned int u = __builtin_bit_cast(unsigned int, f);
  u += 0x7fffu + ((u >> 16) & 1u);
  return (unsigned short)(u >> 16);
}
__device__ __forceinline__ float bf2f(unsigned short h) {
  unsigned int u = ((unsigned int)h) << 16;
  return __builtin_bit_cast(float, u);
}
__device__ __forceinline__ void glds16(const void* g, void* l) {
  __builtin_amdgcn_global_load_lds((const __attribute__((address_space(1))) unsigned*)g,
                                   (__attribute__((address_space(3))) unsigned*)l, 16, 0, 0);
}

// ========== K1: prep = cvt (0..2047) + transposes (2048..3071) + xsum partials ====
// xsum partials: unit 3072+u, u = b*16 + cg*8 + rc. Thread tid sums column
// cg*256+tid of x over rows rc*256..rc*256+255 of batch b -> xpart[u][tid].
__global__ __launch_bounds__(256) void prep_kernel(const float* __restrict__ x,
                                                   const float* __restrict__ Wq,
                                                   const float* __restrict__ Wk,
                                                   const float* __restrict__ Wv,
                                                   const float* __restrict__ Wo,
                                                   unsigned short* __restrict__ xb,
                                                   unsigned short* __restrict__ WqkT,
                                                   unsigned short* __restrict__ WvT,
                                                   unsigned short* __restrict__ WoT,
                                                   float* __restrict__ xpart) {
  __shared__ float t[32][33];
  const int blk = blockIdx.x, tid = threadIdx.x;
  if (blk < 2048) {
    const int base = (blk * 256 + tid) * 8;
    float4 f0 = *(const float4*)(x + base);
    float4 f1 = *(const float4*)(x + base + 4);
    uint4 o;
    o.x = (unsigned)f2bf(f0.x) | ((unsigned)f2bf(f0.y) << 16);
    o.y = (unsigned)f2bf(f0.z) | ((unsigned)f2bf(f0.w) << 16);
    o.z = (unsigned)f2bf(f1.x) | ((unsigned)f2bf(f1.y) << 16);
    o.w = (unsigned)f2bf(f1.z) | ((unsigned)f2bf(f1.w) << 16);
    *(uint4*)(xb + base) = o;
    return;
  }
  if (blk < 3072) {
    const int tb = blk - 2048;
    const int which = tb >> 8, tile = tb & 255;
    const float* W = which == 0 ? Wq : which == 1 ? Wk : which == 2 ? Wv : Wo;
    unsigned short* WT = which == 0 ? WqkT : which == 1 ? (WqkT + 512 * 512)
                        : which == 2 ? WvT : WoT;
    const int tx = tid & 31, ty = tid >> 5;
    const int x0 = (tile & 15) * 32, y0 = (tile >> 4) * 32;
#pragma unroll
    for (int r = 0; r < 4; r++)
      t[ty + 8 * r][tx] = W[(size_t)(y0 + ty + 8 * r) * DMODEL + x0 + tx];
    __syncthreads();
#pragma unroll
    for (int r = 0; r < 4; r++)
      WT[(size_t)(x0 + ty + 8 * r) * DMODEL + y0 + tx] = f2bf(t[tx][ty + 8 * r]);
    return;
  }
  // xsum partial: 64 units
  const int u = blk - 3072;
  const int b = u >> 4, cg = (u >> 3) & 1, rc = u & 7;
  const float* base = x + (size_t)(b * S_LEN + rc * 256) * DMODEL + cg * 256 + tid;
  float s = 0.f;
  for (int j = 0; j < 256; j++) s += base[(size_t)j * DMODEL];
  xpart[u * 256 + tid] = s;
}

// ========== K2: QKV GEMM (units 0..767) + vsum GEMV (units 768..895) ==============
// vsum[b][f] = 2048*bv[f] + dot(xsum[b,:], WvT[f,:]) — independent of Vt, so it
// coexists with the GEMM that produces Vt in the same dispatch.
__global__ __launch_bounds__(256, 2) void qkv_kernel(const unsigned short* __restrict__ xb,
                                                     const unsigned short* __restrict__ WqkT,
                                                     const unsigned short* __restrict__ WvT,
                                                     const float* __restrict__ bq,
                                                     const float* __restrict__ bk,
                                                     const float* __restrict__ bv,
                                                     const int* __restrict__ x_len,
                                                     const float* __restrict__ xpart,
                                                     unsigned short* __restrict__ Qb,
                                                     unsigned short* __restrict__ Kb,
                                                     unsigned short* __restrict__ Vt,
                                                     float* __restrict__ vsum) {
  __shared__ __align__(16) char smem[16384];
  const int bid = blockIdx.x;
  const int tid = threadIdx.x;
  if (bid >= 768) {
    // vsum GEMV unit: u in 0..127, b = u>>5, 16 features per unit (4/wave)
    const int u = bid - 768;
    const int b = u >> 5;
    const int wave = tid >> 6, lane = tid & 63;
    const int cg = lane >> 5, ko = (lane & 31) * 8;
    float xs[8] = {};
#pragma unroll
    for (int rc = 0; rc < 8; rc++) {
      const float* p = xpart + ((b * 16 + cg * 8 + rc) << 8) + ko;
      float4 a0 = *(const float4*)p;
      float4 a1 = *(const float4*)(p + 4);
      xs[0] += a0.x; xs[1] += a0.y; xs[2] += a0.z; xs[3] += a0.w;
      xs[4] += a1.x; xs[5] += a1.y; xs[6] += a1.z; xs[7] += a1.w;
    }
#pragma unroll
    for (int ci = 0; ci < 4; ci++) {
      const int f = (u & 31) * 16 + wave * 4 + ci;
      const uint4 wv = *(const uint4*)(WvT + (size_t)f * DMODEL + lane * 8);
      const unsigned int w[4] = {wv.x, wv.y, wv.z, wv.w};
      float acc = 0.f;
#pragma unroll
      for (int e = 0; e < 4; e++) {
        acc += xs[2 * e] * bf2f((unsigned short)(w[e] & 0xffffu));
        acc += xs[2 * e + 1] * bf2f((unsigned short)(w[e] >> 16));
      }
#pragma unroll
      for (int off = 1; off < 64; off <<= 1) acc += __shfl_xor(acc, off, 64);
      if (lane == 0) vsum[b * DMODEL + f] = acc + 2048.f * bv[f];
    }
    return;
  }
  const bool vmode = bid < 256;
  const unsigned short *A, *Bt;
  int m0, n0;
  if (vmode) {
    m0 = (bid & 3) * 128;   // feature
    n0 = (bid >> 2) * 128;  // row
    A = WvT; Bt = xb;
  } else {
    const int q = bid - 256;
    m0 = (q >> 3) * 128;    // row
    n0 = (q & 7) * 128;     // col (0-511 Q, 512-1023 K)
    A = xb; Bt = WqkT;
    const int xl = x_len[m0 >> 11];
    const int s0 = m0 & 2047;
    if (n0 >= DMODEL) { if (s0 >= xl) return; }   // K rows >= xlen unobserved
    else if (s0 >= xl + 128) return;              // Q rows >= xlen+128 unobserved
  }
  char* As = smem;
  char* Bs = smem + 8192;
  const int wave = tid >> 6, lane = tid & 63;
  const int wr = wave >> 1, wc = wave & 1;
  const int lm = lane & 15, lq = lane >> 4;
  const int lr = lane >> 2;
  const int lc = (lane & 3) ^ ((lane >> 3) & 3);
  const unsigned short* gA0 = A + (size_t)(m0 + wave * 16 + lr) * DMODEL + lc * 8;
  const unsigned short* gA1 = A + (size_t)(m0 + (wave + 4) * 16 + lr) * DMODEL + lc * 8;
  const unsigned short* gB0 = Bt + (size_t)(n0 + wave * 16 + lr) * DMODEL + lc * 8;
  const unsigned short* gB1 = Bt + (size_t)(n0 + (wave + 4) * 16 + lr) * DMODEL + lc * 8;
  char* lA0 = As + wave * 1024 + lane * 16;
  char* lA1 = As + (wave + 4) * 1024 + lane * 16;
  char* lB0 = Bs + wave * 1024 + lane * 16;
  char* lB1 = Bs + (wave + 4) * 1024 + lane * 16;
  const int sw = (lm >> 1) & 3;
  int aoff[4], boff[4];
#pragma unroll
  for (int mi = 0; mi < 4; mi++) aoff[mi] = (wr * 64 + mi * 16 + lm) * 64 + (lq ^ sw) * 16;
#pragma unroll
  for (int ni = 0; ni < 4; ni++) boff[ni] = (wc * 64 + ni * 16 + lm) * 64 + (lq ^ sw) * 16;
  f32x4 acc[4][4] = {};
  for (int k0 = 0; k0 < DMODEL; k0 += 32) {
    __syncthreads();
    glds16(gA0 + k0, lA0);
    glds16(gA1 + k0, lA1);
    glds16(gB0 + k0, lB0);
    glds16(gB1 + k0, lB1);
    __syncthreads();
    short8 af[4], bfr[4];
#pragma unroll
    for (int mi = 0; mi < 4; mi++) af[mi] = *(const short8*)(As + aoff[mi]);
#pragma unroll
    for (int ni = 0; ni < 4; ni++) bfr[ni] = *(const short8*)(Bs + boff[ni]);
#pragma unroll
    for (int mi = 0; mi < 4; mi++)
#pragma unroll
      for (int ni = 0; ni < 4; ni++)
        acc[mi][ni] = __builtin_amdgcn_mfma_f32_16x16x32_bf16(af[mi], bfr[ni], acc[mi][ni], 0, 0, 0);
  }
#pragma unroll
  for (int mi = 0; mi < 4; mi++) {
    const int row0 = m0 + wr * 64 + mi * 16 + lq * 4;
#pragma unroll
    for (int ni = 0; ni < 4; ni++) {
      const int col = n0 + wc * 64 + ni * 16 + lm;
#pragma unroll
      for (int r = 0; r < 4; r++) {
        const int row = row0 + r;
        const float v = acc[mi][ni][r];
        if (vmode) {
          Vt[(size_t)row * ROWS + col] = f2bf(v + bv[row]);
        } else if (col < DMODEL) {
          Qb[(size_t)row * DMODEL + col] = f2bf(v + bq[col]);
        } else {
          Kb[(size_t)row * DMODEL + (col - DMODEL)] = f2bf(v + bk[col - DMODEL]);
        }
      }
    }
  }
}

// ========== K3: banded attention (units 0..1023) + tailrow (1024..1087) ===========
__global__ __launch_bounds__(256) void attn_kernel(const unsigned short* __restrict__ Q,
                                                   const unsigned short* __restrict__ K,
                                                   const unsigned short* __restrict__ Vt,
                                                   const int* __restrict__ x_len,
                                                   const float* __restrict__ vsum,
                                                   const unsigned short* __restrict__ WoT,
                                                   const float* __restrict__ bo,
                                                   float* __restrict__ trow,
                                                   unsigned short* __restrict__ ctx) {
  __shared__ unsigned short Ks[32][72];     // 32 keys x 64 dims (+pad)
  __shared__ unsigned short Vs[64][40];     // 64 dims x 32 keys (+pad)
  __shared__ unsigned short Ps[4][16][40];  // per-wave P roundtrip (C->A layout)
  const int tid = threadIdx.x;
  const int unit = blockIdx.x;
  const int wave = tid >> 6, lane = tid & 63;
  if (unit >= 1024) {
    // tailrow: trow[b][c] = bo[c] + (vsum[b]/2048) . WoT[c]
    const int u = unit - 1024;
    const int b = u >> 4;
    const float* vs = vsum + b * DMODEL + lane * 8;
    float vreg[8];
    *(float4*)vreg = *(const float4*)vs;
    *(float4*)(vreg + 4) = *(const float4*)(vs + 4);
#pragma unroll
    for (int ci = 0; ci < 8; ci++) {
      const int c = (u & 15) * 32 + wave * 8 + ci;
      const uint4 wv = *(const uint4*)(WoT + (size_t)c * DMODEL + lane * 8);
      const unsigned int w[4] = {wv.x, wv.y, wv.z, wv.w};
      float acc = 0.f;
#pragma unroll
      for (int e = 0; e < 4; e++) {
        acc += vreg[2 * e] * bf2f((unsigned short)(w[e] & 0xffffu));
        acc += vreg[2 * e + 1] * bf2f((unsigned short)(w[e] >> 16));
      }
#pragma unroll
      for (int off = 1; off < 64; off <<= 1) acc += __shfl_xor(acc, off, 64);
      if (lane == 0) trow[b * DMODEL + c] = bo[c] + acc * (1.f / 2048.f);
    }
    return;
  }
  const int b = unit >> 8, h = (unit >> 5) & 7;
  const int i0 = (unit & 31) * 64;
  const int xlen = x_len[b];
  const int t0 = min(S_LEN, xlen + 128);
  if ((i0 & ~127) >= t0) return; // whole 128-slab is tail: K4 broadcasts it
  const int lm = lane & 15, lq = lane >> 4;
  const int q0 = i0 + wave * 16;
  const size_t qoff = (size_t)(b * S_LEN + q0 + lm) * DMODEL + h * HDIM + lq * 8;
  const short8 aq0 = *(const short8*)(Q + qoff);
  const short8 aq1 = *(const short8*)(Q + qoff + 32);
  const int krow = tid >> 3, kchk = (tid & 7) * 8;
  const int vdim = tid >> 2, vchk = (tid & 3) * 8;
  f32x4 oacc[4] = {};
  float lrow[4] = {0.f, 0.f, 0.f, 0.f};
  for (int kt = 0; kt < 10; kt++) {
    const int jt0 = i0 - 128 + kt * 32;
    if (jt0 + 31 < 0 || jt0 >= xlen) continue;
    __syncthreads();
    {
      const int jr = jt0 + krow;
      const int jrc = min(max(jr, 0), S_LEN - 1);
      *(uint4*)&Ks[krow][kchk] =
          *(const uint4*)(K + (size_t)(b * S_LEN + jrc) * DMODEL + h * HDIM + kchk);
      const int jv = jt0 + vchk;
      const int jvc = min(max(jv, 0), S_LEN - 8);
      *(uint4*)&Vs[vdim][vchk] =
          *(const uint4*)(Vt + (size_t)(h * HDIM + vdim) * ROWS + b * S_LEN + jvc);
    }
    __syncthreads();
    if (jt0 + 31 < q0 - 128 || jt0 > q0 + 143) continue;
    f32x4 sv[2];
#pragma unroll
    for (int sub = 0; sub < 2; sub++) {
      const short8 bk0 = *(const short8*)&Ks[sub * 16 + lm][lq * 8];
      const short8 bk1 = *(const short8*)&Ks[sub * 16 + lm][32 + lq * 8];
      f32x4 s = {};
      s = __builtin_amdgcn_mfma_f32_16x16x32_bf16(aq0, bk0, s, 0, 0, 0);
      s = __builtin_amdgcn_mfma_f32_16x16x32_bf16(aq1, bk1, s, 0, 0, 0);
      sv[sub] = s;
    }
    float p[2][4];
#pragma unroll
    for (int sub = 0; sub < 2; sub++) {
      const int j = jt0 + sub * 16 + lm;
      const bool jv = (j >= 0) && (j < xlen);
#pragma unroll
      for (int r = 0; r < 4; r++) {
        const int i = q0 + lq * 4 + r;
        const bool ok = jv && (j - i <= 128) && (i - j <= 128);
        const float pv = ok ? __expf(sv[sub][r] * 0.125f) : 0.f;
        p[sub][r] = pv;
        lrow[r] += pv;
      }
    }
#pragma unroll
    for (int r = 0; r < 4; r++) {
      Ps[wave][lq * 4 + r][lm] = f2bf(p[0][r]);
      Ps[wave][lq * 4 + r][16 + lm] = f2bf(p[1][r]);
    }
    const short8 pf = *(const short8*)&Ps[wave][lm][lq * 8];
#pragma unroll
    for (int dt = 0; dt < 4; dt++) {
      const short8 bv = *(const short8*)&Vs[dt * 16 + lm][lq * 8];
      oacc[dt] = __builtin_amdgcn_mfma_f32_16x16x32_bf16(pf, bv, oacc[dt], 0, 0, 0);
    }
  }
#pragma unroll
  for (int r = 0; r < 4; r++)
#pragma unroll
    for (int off = 1; off < 16; off <<= 1) lrow[r] += __shfl_xor(lrow[r], off, 64);
#pragma unroll
  for (int r = 0; r < 4; r++) {
    const int i = q0 + lq * 4 + r;
    const size_t obase = (size_t)(b * S_LEN + i) * DMODEL + h * HDIM;
    if (lrow[r] > 0.f) {
      const float inv = 1.f / lrow[r];
#pragma unroll
      for (int dt = 0; dt < 4; dt++)
        ctx[obase + dt * 16 + lm] = f2bf(oacc[dt][r] * inv);
    } else {
      // all keys masked -> reference softmax exactly uniform over ALL 2048 keys
#pragma unroll
      for (int dt = 0; dt < 4; dt++)
        ctx[obase + dt * 16 + lm] =
            f2bf(vsum[(size_t)b * DMODEL + h * HDIM + dt * 16 + lm] * (1.f / 2048.f));
    }
  }
}

// ========== K4: output projection; tail slabs broadcast trow ======================
__global__ __launch_bounds__(256, 2) void out_kernel(const unsigned short* __restrict__ A,
                                                     const unsigned short* __restrict__ Bt,
                                                     const float* __restrict__ bias,
                                                     const int* __restrict__ x_len,
                                                     const float* __restrict__ trow,
                                                     float* __restrict__ out) {
  __shared__ __align__(16) char smem[16384];
  const int tid = threadIdx.x;
  const int m0 = (blockIdx.x >> 2) * 128, n0 = (blockIdx.x & 3) * 128;
  const int xl = x_len[m0 >> 11];
  if ((m0 & 2047) >= min(S_LEN, xl + 128)) {
    const float4 val = *(const float4*)(trow + (m0 >> 11) * DMODEL + n0 + (tid & 31) * 4);
    float* obase = out + (size_t)m0 * DMODEL + n0 + (tid & 31) * 4;
#pragma unroll
    for (int r = tid >> 5; r < 128; r += 8)
      *(float4*)(obase + (size_t)r * DMODEL) = val;
    return;
  }
  char* As = smem;
  char* Bs = smem + 8192;
  const int wave = tid >> 6, lane = tid & 63;
  const int wr = wave >> 1, wc = wave & 1;
  const int lm = lane & 15, lq = lane >> 4;
  const int lr = lane >> 2;
  const int lc = (lane & 3) ^ ((lane >> 3) & 3);
  const unsigned short* gA0 = A + (size_t)(m0 + wave * 16 + lr) * DMODEL + lc * 8;
  const unsigned short* gA1 = A + (size_t)(m0 + (wave + 4) * 16 + lr) * DMODEL + lc * 8;
  const unsigned short* gB0 = Bt + (size_t)(n0 + wave * 16 + lr) * DMODEL + lc * 8;
  const unsigned short* gB1 = Bt + (size_t)(n0 + (wave + 4) * 16 + lr) * DMODEL + lc * 8;
  char* lA0 = As + wave * 1024 + lane * 16;
  char* lA1 = As + (wave + 4) * 1024 + lane * 16;
  char* lB0 = Bs + wave * 1024 + lane * 16;
  char* lB1 = Bs + (wave + 4) * 1024 + lane * 16;
  const int sw = (lm >> 1) & 3;
  int aoff[4], boff[4];
#pragma unroll
  for (int mi = 0; mi < 4; mi++) aoff[mi] = (wr * 64 + mi * 16 + lm) * 64 + (lq ^ sw) * 16;
#pragma unroll
  for (int ni = 0; ni < 4; ni++) boff[ni] = (wc * 64 + ni * 16 + lm) * 64 + (lq ^ sw) * 16;
  f32x4 acc[4][4] = {};
  for (int k0 = 0; k0 < DMODEL; k0 += 32) {
    __syncthreads();
    glds16(gA0 + k0, lA0);
    glds16(gA1 + k0, lA1);
    glds16(gB0 + k0, lB0);
    glds16(gB1 + k0, lB1);
    __syncthreads();
    short8 af[4], bfr[4];
#pragma unroll
    for (int mi = 0; mi < 4; mi++) af[mi] = *(const short8*)(As + aoff[mi]);
#pragma unroll
    for (int ni = 0; ni < 4; ni++) bfr[ni] = *(const short8*)(Bs + boff[ni]);
#pragma unroll
    for (int mi = 0; mi < 4; mi++)
#pragma unroll
      for (int ni = 0; ni < 4; ni++)
        acc[mi][ni] = __builtin_amdgcn_mfma_f32_16x16x32_bf16(af[mi], bfr[ni], acc[mi][ni], 0, 0, 0);
  }
#pragma unroll
  for (int mi = 0; mi < 4; mi++) {
    const int row0 = m0 + wr * 64 + mi * 16 + lq * 4;
#pragma unroll
    for (int ni = 0; ni < 4; ni++) {
      const int col = n0 + wc * 64 + ni * 16 + lm;
#pragma unroll
      for (int r = 0; r < 4; r++)
        out[(size_t)(row0 + r) * DMODEL + col] = acc[mi][ni][r] + bias[col];
    }
  }
}

extern "C" void kernel_launch(void* const* d_in, const int* in_sizes, int n_in,
                              void* d_out, int out_size, void* d_ws, size_t ws_size,
                              hipStream_t stream) {
  (void)in_sizes; (void)n_in; (void)out_size; (void)ws_size;
  const float* x  = (const float*)d_in[0];
  const float* Wq = (const float*)d_in[1];
  const float* bq = (const float*)d_in[2];
  const float* Wk = (const float*)d_in[3];
  const float* bk = (const float*)d_in[4];
  const float* Wv = (const float*)d_in[5];
  const float* bv = (const float*)d_in[6];
  const float* Wo = (const float*)d_in[7];
  const float* bo = (const float*)d_in[8];
  const int* x_len = (const int*)d_in[9];

  char* ws = (char*)d_ws;
  const size_t MB = 1024 * 1024;
  unsigned short* xb   = (unsigned short*)(ws + 0 * MB);   // [8192][512]
  unsigned short* Qb   = (unsigned short*)(ws + 8 * MB);   // [8192][512]
  unsigned short* Kb   = (unsigned short*)(ws + 16 * MB);  // [8192][512]
  unsigned short* Vt   = (unsigned short*)(ws + 24 * MB);  // [512][8192]
  unsigned short* Cx   = (unsigned short*)(ws + 32 * MB);  // [8192][512]
  unsigned short* WqkT = (unsigned short*)(ws + 40 * MB);  // [1024][512]: Wq^T | Wk^T
  unsigned short* WvT  = (unsigned short*)(ws + 41 * MB);  // [512][512]
  unsigned short* WoT  = (unsigned short*)(ws + 41 * MB + 512 * 1024);
  float* vsum          = (float*)(ws + 42 * MB);           // [4][512]
  float* trow          = (float*)(ws + 42 * MB + 8192);    // [4][512]
  float* xpart         = (float*)(ws + 43 * MB);           // [64][256]

  prep_kernel<<<3136, 256, 0, stream>>>(x, Wq, Wk, Wv, Wo, xb, WqkT, WvT, WoT, xpart);
  qkv_kernel<<<896, 256, 0, stream>>>(xb, WqkT, WvT, bq, bk, bv, x_len, xpart,
                                      Qb, Kb, Vt, vsum);
  attn_kernel<<<1088, 256, 0, stream>>>(Qb, Kb, Vt, x_len, vsum, WoT, bo, trow, Cx);
  out_kernel<<<256, 256, 0, stream>>>(Cx, WoT, bo, x_len, trow, (float*)d_out);
}

// Round 11
// 147.302 us; speedup vs baseline: 2.7947x; 1.0193x over previous
//
#include <hip/hip_runtime.h>

#define S_LEN 2048
#define BATCH 4
#define DMODEL 512
#define NHEAD 8
#define HDIM 64
#define ROWS (BATCH * S_LEN) /* 8192 */

using short8 = __attribute__((ext_vector_type(8))) short;
using f32x4  = __attribute__((ext_vector_type(4))) float;

__device__ __forceinline__ unsigned short f2bf(float f) {
  unsigned int u = __builtin_bit_cast(unsigned int, f);
  u += 0x7fffu + ((u >> 16) & 1u);
  return (unsigned short)(u >> 16);
}
__device__ __forceinline__ float bf2f(unsigned short h) {
  unsigned int u = ((unsigned int)h) << 16;
  return __builtin_bit_cast(float, u);
}
__device__ __forceinline__ void glds16(const void* g, void* l) {
  __builtin_amdgcn_global_load_lds((const __attribute__((address_space(1))) unsigned*)g,
                                   (__attribute__((address_space(3))) unsigned*)l, 16, 0, 0);
}

// ========== K1: prep = cvt (0..2047) + transposes (2048..3071) + xsum partials ====
__global__ __launch_bounds__(256) void prep_kernel(const float* __restrict__ x,
                                                   const float* __restrict__ Wq,
                                                   const float* __restrict__ Wk,
                                                   const float* __restrict__ Wv,
                                                   const float* __restrict__ Wo,
                                                   unsigned short* __restrict__ xb,
                                                   unsigned short* __restrict__ WqkT,
                                                   unsigned short* __restrict__ WvT,
                                                   unsigned short* __restrict__ WoT,
                                                   float* __restrict__ xpart) {
  __shared__ float t[32][33];
  const int blk = blockIdx.x, tid = threadIdx.x;
  if (blk < 2048) {
    const int base = (blk * 256 + tid) * 8;
    float4 f0 = *(const float4*)(x + base);
    float4 f1 = *(const float4*)(x + base + 4);
    uint4 o;
    o.x = (unsigned)f2bf(f0.x) | ((unsigned)f2bf(f0.y) << 16);
    o.y = (unsigned)f2bf(f0.z) | ((unsigned)f2bf(f0.w) << 16);
    o.z = (unsigned)f2bf(f1.x) | ((unsigned)f2bf(f1.y) << 16);
    o.w = (unsigned)f2bf(f1.z) | ((unsigned)f2bf(f1.w) << 16);
    *(uint4*)(xb + base) = o;
    return;
  }
  if (blk < 3072) {
    const int tb = blk - 2048;
    const int which = tb >> 8, tile = tb & 255;
    const float* W = which == 0 ? Wq : which == 1 ? Wk : which == 2 ? Wv : Wo;
    unsigned short* WT = which == 0 ? WqkT : which == 1 ? (WqkT + 512 * 512)
                        : which == 2 ? WvT : WoT;
    const int tx = tid & 31, ty = tid >> 5;
    const int x0 = (tile & 15) * 32, y0 = (tile >> 4) * 32;
#pragma unroll
    for (int r = 0; r < 4; r++)
      t[ty + 8 * r][tx] = W[(size_t)(y0 + ty + 8 * r) * DMODEL + x0 + tx];
    __syncthreads();
#pragma unroll
    for (int r = 0; r < 4; r++)
      WT[(size_t)(x0 + ty + 8 * r) * DMODEL + y0 + tx] = f2bf(t[tx][ty + 8 * r]);
    return;
  }
  const int u = blk - 3072; // 64 xsum-partial units
  const int b = u >> 4, cg = (u >> 3) & 1, rc = u & 7;
  const float* base = x + (size_t)(b * S_LEN + rc * 256) * DMODEL + cg * 256 + tid;
  float s = 0.f;
  for (int j = 0; j < 256; j++) s += base[(size_t)j * DMODEL];
  xpart[u * 256 + tid] = s;
}

// ========== K2: QKV GEMM, BK=64 (units 0..767) + vsum GEMV (768..895) =============
// BK=64: 8 barrier rounds of 32 MFMA (vs 16 rounds of 16) — halves the structural
// vmcnt(0)+s_barrier drains that dominate at K=512.
__global__ __launch_bounds__(256, 2) void qkv_kernel(const unsigned short* __restrict__ xb,
                                                     const unsigned short* __restrict__ WqkT,
                                                     const unsigned short* __restrict__ WvT,
                                                     const float* __restrict__ bq,
                                                     const float* __restrict__ bk,
                                                     const float* __restrict__ bv,
                                                     const int* __restrict__ x_len,
                                                     const float* __restrict__ xpart,
                                                     unsigned short* __restrict__ Qb,
                                                     unsigned short* __restrict__ Kb,
                                                     unsigned short* __restrict__ Vt,
                                                     float* __restrict__ vsum) {
  __shared__ __align__(16) char smem[32768];
  const int bid = blockIdx.x;
  const int tid = threadIdx.x;
  const int wave = tid >> 6, lane = tid & 63;
  if (bid >= 768) {
    // vsum[b][f] = 2048*bv[f] + dot(xsum[b,:], WvT[f,:])  (independent of Vt)
    const int u = bid - 768;
    const int b = u >> 5;
    const int cg = lane >> 5, ko = (lane & 31) * 8;
    float xs[8] = {};
#pragma unroll
    for (int rc = 0; rc < 8; rc++) {
      const float* p = xpart + ((b * 16 + cg * 8 + rc) << 8) + ko;
      float4 a0 = *(const float4*)p;
      float4 a1 = *(const float4*)(p + 4);
      xs[0] += a0.x; xs[1] += a0.y; xs[2] += a0.z; xs[3] += a0.w;
      xs[4] += a1.x; xs[5] += a1.y; xs[6] += a1.z; xs[7] += a1.w;
    }
#pragma unroll
    for (int ci = 0; ci < 4; ci++) {
      const int f = (u & 31) * 16 + wave * 4 + ci;
      const uint4 wv = *(const uint4*)(WvT + (size_t)f * DMODEL + lane * 8);
      const unsigned int w[4] = {wv.x, wv.y, wv.z, wv.w};
      float acc = 0.f;
#pragma unroll
      for (int e = 0; e < 4; e++) {
        acc += xs[2 * e] * bf2f((unsigned short)(w[e] & 0xffffu));
        acc += xs[2 * e + 1] * bf2f((unsigned short)(w[e] >> 16));
      }
#pragma unroll
      for (int off = 1; off < 64; off <<= 1) acc += __shfl_xor(acc, off, 64);
      if (lane == 0) vsum[b * DMODEL + f] = acc + 2048.f * bv[f];
    }
    return;
  }
  const bool vmode = bid < 256;
  const unsigned short *A, *Bt;
  int m0, n0;
  if (vmode) {
    m0 = (bid & 3) * 128;   // feature
    n0 = (bid >> 2) * 128;  // row
    A = WvT; Bt = xb;
    // V rows >= xlen are never observed (p==0 multiplies them; vsum comes from x)
    if ((n0 & 2047) >= x_len[n0 >> 11]) return;
  } else {
    const int q = bid - 256;
    m0 = (q >> 3) * 128;    // row
    n0 = (q & 7) * 128;     // col (0-511 Q, 512-1023 K)
    A = xb; Bt = WqkT;
    const int xl = x_len[m0 >> 11];
    const int s0 = m0 & 2047;
    if (n0 >= DMODEL) { if (s0 >= xl) return; }   // K rows >= xlen unobserved
    else if (s0 >= xl + 128) return;              // Q rows >= xlen+128 unobserved
  }
  char* As = smem;            // [128][64] bf16, phys chunk = logical ^ (row&7)
  char* Bs = smem + 16384;
  const int wr = wave >> 1, wc = wave & 1;
  const int lm = lane & 15, lq = lane >> 4;
  const int srow = lane >> 3;                 // row within 8-row staging group
  const int slc = (lane & 7) ^ (srow & 7);    // logical chunk at phys slot lane&7
  const unsigned short* gA[4];
  const unsigned short* gB[4];
  char *lA[4], *lB[4];
#pragma unroll
  for (int i = 0; i < 4; i++) {
    const int g = wave * 4 + i;
    gA[i] = A + (size_t)(m0 + g * 8 + srow) * DMODEL + slc * 8;
    gB[i] = Bt + (size_t)(n0 + g * 8 + srow) * DMODEL + slc * 8;
    lA[i] = As + g * 1024 + lane * 16;
    lB[i] = Bs + g * 1024 + lane * 16;
  }
  int aoff[4][2], boff[4][2];
#pragma unroll
  for (int mi = 0; mi < 4; mi++)
#pragma unroll
    for (int h = 0; h < 2; h++) {
      aoff[mi][h] = (wr * 64 + mi * 16 + lm) * 128 + ((((h << 2) | lq)) ^ (lm & 7)) * 16;
      boff[mi][h] = (wc * 64 + mi * 16 + lm) * 128 + ((((h << 2) | lq)) ^ (lm & 7)) * 16;
    }
  f32x4 acc[4][4] = {};
  for (int k0 = 0; k0 < DMODEL; k0 += 64) {
    __syncthreads();
#pragma unroll
    for (int i = 0; i < 4; i++) {
      glds16(gA[i] + k0, lA[i]);
      glds16(gB[i] + k0, lB[i]);
    }
    __syncthreads();
#pragma unroll
    for (int h = 0; h < 2; h++) {
      short8 af[4], bfr[4];
#pragma unroll
      for (int mi = 0; mi < 4; mi++) af[mi] = *(const short8*)(As + aoff[mi][h]);
#pragma unroll
      for (int ni = 0; ni < 4; ni++) bfr[ni] = *(const short8*)(Bs + boff[ni][h]);
#pragma unroll
      for (int mi = 0; mi < 4; mi++)
#pragma unroll
        for (int ni = 0; ni < 4; ni++)
          acc[mi][ni] = __builtin_amdgcn_mfma_f32_16x16x32_bf16(af[mi], bfr[ni], acc[mi][ni], 0, 0, 0);
    }
  }
#pragma unroll
  for (int mi = 0; mi < 4; mi++) {
    const int row0 = m0 + wr * 64 + mi * 16 + lq * 4;
#pragma unroll
    for (int ni = 0; ni < 4; ni++) {
      const int col = n0 + wc * 64 + ni * 16 + lm;
#pragma unroll
      for (int r = 0; r < 4; r++) {
        const int row = row0 + r;
        const float v = acc[mi][ni][r];
        if (vmode) {
          Vt[(size_t)row * ROWS + col] = f2bf(v + bv[row]);
        } else if (col < DMODEL) {
          Qb[(size_t)row * DMODEL + col] = f2bf(v + bq[col]);
        } else {
          Kb[(size_t)row * DMODEL + (col - DMODEL)] = f2bf(v + bk[col - DMODEL]);
        }
      }
    }
  }
}

// ========== K3: banded attention, 64-key tiles (units 0..1023) + tailrow ==========
// 5 staging/barrier rounds (was 10), same bytes and MFMA count per block.
__global__ __launch_bounds__(256) void attn_kernel(const unsigned short* __restrict__ Q,
                                                   const unsigned short* __restrict__ K,
                                                   const unsigned short* __restrict__ Vt,
                                                   const int* __restrict__ x_len,
                                                   const float* __restrict__ vsum,
                                                   const unsigned short* __restrict__ WoT,
                                                   const float* __restrict__ bo,
                                                   float* __restrict__ trow,
                                                   unsigned short* __restrict__ ctx) {
  __shared__ unsigned short Ks[64][72];     // 64 keys x 64 dims (+pad)
  __shared__ unsigned short Vs[64][72];     // 64 dims x 64 keys (+pad)
  __shared__ unsigned short Ps[4][16][72];  // per-wave P roundtrip (C->A layout)
  const int tid = threadIdx.x;
  const int unit = blockIdx.x;
  const int wave = tid >> 6, lane = tid & 63;
  if (unit >= 1024) {
    // tailrow: trow[b][c] = bo[c] + (vsum[b]/2048) . WoT[c]
    const int u = unit - 1024;
    const int b = u >> 4;
    const float* vs = vsum + b * DMODEL + lane * 8;
    float vreg[8];
    *(float4*)vreg = *(const float4*)vs;
    *(float4*)(vreg + 4) = *(const float4*)(vs + 4);
#pragma unroll
    for (int ci = 0; ci < 8; ci++) {
      const int c = (u & 15) * 32 + wave * 8 + ci;
      const uint4 wv = *(const uint4*)(WoT + (size_t)c * DMODEL + lane * 8);
      const unsigned int w[4] = {wv.x, wv.y, wv.z, wv.w};
      float acc = 0.f;
#pragma unroll
      for (int e = 0; e < 4; e++) {
        acc += vreg[2 * e] * bf2f((unsigned short)(w[e] & 0xffffu));
        acc += vreg[2 * e + 1] * bf2f((unsigned short)(w[e] >> 16));
      }
#pragma unroll
      for (int off = 1; off < 64; off <<= 1) acc += __shfl_xor(acc, off, 64);
      if (lane == 0) trow[b * DMODEL + c] = bo[c] + acc * (1.f / 2048.f);
    }
    return;
  }
  const int b = unit >> 8, h = (unit >> 5) & 7;
  const int i0 = (unit & 31) * 64;
  const int xlen = x_len[b];
  const int t0 = min(S_LEN, xlen + 128);
  if ((i0 & ~127) >= t0) return; // whole 128-slab is tail: K4 broadcasts it
  const int lm = lane & 15, lq = lane >> 4;
  const int q0 = i0 + wave * 16;
  const size_t qoff = (size_t)(b * S_LEN + q0 + lm) * DMODEL + h * HDIM + lq * 8;
  const short8 aq0 = *(const short8*)(Q + qoff);
  const short8 aq1 = *(const short8*)(Q + qoff + 32);
  const int sr = tid >> 3, sc = (tid & 7) * 8; // staging: 2 rows/dims per thread
  f32x4 oacc[4] = {};
  float lrow[4] = {0.f, 0.f, 0.f, 0.f};
  for (int kt = 0; kt < 5; kt++) {
    const int jt0 = i0 - 128 + kt * 64;
    if (jt0 + 63 < 0 || jt0 >= xlen) continue; // block-uniform: tile fully masked
    __syncthreads();                           // previous tile's LDS reads done
    {
      const int jr0 = min(max(jt0 + sr, 0), S_LEN - 1);
      const int jr1 = min(max(jt0 + sr + 32, 0), S_LEN - 1);
      *(uint4*)&Ks[sr][sc] =
          *(const uint4*)(K + (size_t)(b * S_LEN + jr0) * DMODEL + h * HDIM + sc);
      *(uint4*)&Ks[sr + 32][sc] =
          *(const uint4*)(K + (size_t)(b * S_LEN + jr1) * DMODEL + h * HDIM + sc);
      const int jvc = min(max(jt0 + sc, 0), S_LEN - 8);
      *(uint4*)&Vs[sr][sc] =
          *(const uint4*)(Vt + (size_t)(h * HDIM + sr) * ROWS + b * S_LEN + jvc);
      *(uint4*)&Vs[sr + 32][sc] =
          *(const uint4*)(Vt + (size_t)(h * HDIM + sr + 32) * ROWS + b * S_LEN + jvc);
    }
    __syncthreads();
    // wave skip: tile outside this wave's band window
    if (jt0 + 63 < q0 - 128 || jt0 > q0 + 143) continue;

    f32x4 sv[4];
#pragma unroll
    for (int sub = 0; sub < 4; sub++) {
      const short8 bk0 = *(const short8*)&Ks[sub * 16 + lm][lq * 8];
      const short8 bk1 = *(const short8*)&Ks[sub * 16 + lm][32 + lq * 8];
      f32x4 s = {};
      s = __builtin_amdgcn_mfma_f32_16x16x32_bf16(aq0, bk0, s, 0, 0, 0);
      s = __builtin_amdgcn_mfma_f32_16x16x32_bf16(aq1, bk1, s, 0, 0, 0);
      sv[sub] = s;
    }
    float p[4][4];
#pragma unroll
    for (int sub = 0; sub < 4; sub++) {
      const int j = jt0 + sub * 16 + lm;
      const bool jv = (j >= 0) && (j < xlen);
#pragma unroll
      for (int r = 0; r < 4; r++) {
        const int i = q0 + lq * 4 + r;
        const bool ok = jv && (j - i <= 128) && (i - j <= 128);
        const float pv = ok ? __expf(sv[sub][r] * 0.125f) : 0.f;
        p[sub][r] = pv;
        lrow[r] += pv;
      }
    }
#pragma unroll
    for (int sub = 0; sub < 4; sub++)
#pragma unroll
      for (int r = 0; r < 4; r++)
        Ps[wave][lq * 4 + r][sub * 16 + lm] = f2bf(p[sub][r]);
    // within-wave DS write->read is in program order: no barrier needed
    const short8 pf0 = *(const short8*)&Ps[wave][lm][lq * 8];
    const short8 pf1 = *(const short8*)&Ps[wave][lm][32 + lq * 8];
#pragma unroll
    for (int dt = 0; dt < 4; dt++) {
      const short8 bv0 = *(const short8*)&Vs[dt * 16 + lm][lq * 8];
      const short8 bv1 = *(const short8*)&Vs[dt * 16 + lm][32 + lq * 8];
      oacc[dt] = __builtin_amdgcn_mfma_f32_16x16x32_bf16(pf0, bv0, oacc[dt], 0, 0, 0);
      oacc[dt] = __builtin_amdgcn_mfma_f32_16x16x32_bf16(pf1, bv1, oacc[dt], 0, 0, 0);
    }
  }
#pragma unroll
  for (int r = 0; r < 4; r++)
#pragma unroll
    for (int off = 1; off < 16; off <<= 1) lrow[r] += __shfl_xor(lrow[r], off, 64);
#pragma unroll
  for (int r = 0; r < 4; r++) {
    const int i = q0 + lq * 4 + r;
    const size_t obase = (size_t)(b * S_LEN + i) * DMODEL + h * HDIM;
    if (lrow[r] > 0.f) {
      const float inv = 1.f / lrow[r];
#pragma unroll
      for (int dt = 0; dt < 4; dt++)
        ctx[obase + dt * 16 + lm] = f2bf(oacc[dt][r] * inv);
    } else {
      // all keys masked -> reference softmax exactly uniform over ALL 2048 keys
#pragma unroll
      for (int dt = 0; dt < 4; dt++)
        ctx[obase + dt * 16 + lm] =
            f2bf(vsum[(size_t)b * DMODEL + h * HDIM + dt * 16 + lm] * (1.f / 2048.f));
    }
  }
}

// ========== K4: output projection, BK=64; tail slabs broadcast trow ===============
__global__ __launch_bounds__(256, 2) void out_kernel(const unsigned short* __restrict__ A,
                                                     const unsigned short* __restrict__ Bt,
                                                     const float* __restrict__ bias,
                                                     const int* __restrict__ x_len,
                                                     const float* __restrict__ trow,
                                                     float* __restrict__ out) {
  __shared__ __align__(16) char smem[32768];
  const int tid = threadIdx.x;
  const int m0 = (blockIdx.x >> 2) * 128, n0 = (blockIdx.x & 3) * 128;
  const int xl = x_len[m0 >> 11];
  if ((m0 & 2047) >= min(S_LEN, xl + 128)) {
    const float4 val = *(const float4*)(trow + (m0 >> 11) * DMODEL + n0 + (tid & 31) * 4);
    float* obase = out + (size_t)m0 * DMODEL + n0 + (tid & 31) * 4;
#pragma unroll
    for (int r = tid >> 5; r < 128; r += 8)
      *(float4*)(obase + (size_t)r * DMODEL) = val;
    return;
  }
  char* As = smem;
  char* Bs = smem + 16384;
  const int wave = tid >> 6, lane = tid & 63;
  const int wr = wave >> 1, wc = wave & 1;
  const int lm = lane & 15, lq = lane >> 4;
  const int srow = lane >> 3;
  const int slc = (lane & 7) ^ (srow & 7);
  const unsigned short* gA[4];
  const unsigned short* gB[4];
  char *lA[4], *lB[4];
#pragma unroll
  for (int i = 0; i < 4; i++) {
    const int g = wave * 4 + i;
    gA[i] = A + (size_t)(m0 + g * 8 + srow) * DMODEL + slc * 8;
    gB[i] = Bt + (size_t)(n0 + g * 8 + srow) * DMODEL + slc * 8;
    lA[i] = As + g * 1024 + lane * 16;
    lB[i] = Bs + g * 1024 + lane * 16;
  }
  int aoff[4][2], boff[4][2];
#pragma unroll
  for (int mi = 0; mi < 4; mi++)
#pragma unroll
    for (int h = 0; h < 2; h++) {
      aoff[mi][h] = (wr * 64 + mi * 16 + lm) * 128 + ((((h << 2) | lq)) ^ (lm & 7)) * 16;
      boff[mi][h] = (wc * 64 + mi * 16 + lm) * 128 + ((((h << 2) | lq)) ^ (lm & 7)) * 16;
    }
  f32x4 acc[4][4] = {};
  for (int k0 = 0; k0 < DMODEL; k0 += 64) {
    __syncthreads();
#pragma unroll
    for (int i = 0; i < 4; i++) {
      glds16(gA[i] + k0, lA[i]);
      glds16(gB[i] + k0, lB[i]);
    }
    __syncthreads();
#pragma unroll
    for (int h = 0; h < 2; h++) {
      short8 af[4], bfr[4];
#pragma unroll
      for (int mi = 0; mi < 4; mi++) af[mi] = *(const short8*)(As + aoff[mi][h]);
#pragma unroll
      for (int ni = 0; ni < 4; ni++) bfr[ni] = *(const short8*)(Bs + boff[ni][h]);
#pragma unroll
      for (int mi = 0; mi < 4; mi++)
#pragma unroll
        for (int ni = 0; ni < 4; ni++)
          acc[mi][ni] = __builtin_amdgcn_mfma_f32_16x16x32_bf16(af[mi], bfr[ni], acc[mi][ni], 0, 0, 0);
    }
  }
#pragma unroll
  for (int mi = 0; mi < 4; mi++) {
    const int row0 = m0 + wr * 64 + mi * 16 + lq * 4;
#pragma unroll
    for (int ni = 0; ni < 4; ni++) {
      const int col = n0 + wc * 64 + ni * 16 + lm;
#pragma unroll
      for (int r = 0; r < 4; r++)
        out[(size_t)(row0 + r) * DMODEL + col] = acc[mi][ni][r] + bias[col];
    }
  }
}

extern "C" void kernel_launch(void* const* d_in, const int* in_sizes, int n_in,
                              void* d_out, int out_size, void* d_ws, size_t ws_size,
                              hipStream_t stream) {
  (void)in_sizes; (void)n_in; (void)out_size; (void)ws_size;
  const float* x  = (const float*)d_in[0];
  const float* Wq = (const float*)d_in[1];
  const float* bq = (const float*)d_in[2];
  const float* Wk = (const float*)d_in[3];
  const float* bk = (const float*)d_in[4];
  const float* Wv = (const float*)d_in[5];
  const float* bv = (const float*)d_in[6];
  const float* Wo = (const float*)d_in[7];
  const float* bo = (const float*)d_in[8];
  const int* x_len = (const int*)d_in[9];

  char* ws = (char*)d_ws;
  const size_t MB = 1024 * 1024;
  unsigned short* xb   = (unsigned short*)(ws + 0 * MB);   // [8192][512]
  unsigned short* Qb   = (unsigned short*)(ws + 8 * MB);   // [8192][512]
  unsigned short* Kb   = (unsigned short*)(ws + 16 * MB);  // [8192][512]
  unsigned short* Vt   = (unsigned short*)(ws + 24 * MB);  // [512][8192]
  unsigned short* Cx   = (unsigned short*)(ws + 32 * MB);  // [8192][512]
  unsigned short* WqkT = (unsigned short*)(ws + 40 * MB);  // [1024][512]: Wq^T | Wk^T
  unsigned short* WvT  = (unsigned short*)(ws + 41 * MB);  // [512][512]
  unsigned short* WoT  = (unsigned short*)(ws + 41 * MB + 512 * 1024);
  float* vsum          = (float*)(ws + 42 * MB);           // [4][512]
  float* trow          = (float*)(ws + 42 * MB + 8192);    // [4][512]
  float* xpart         = (float*)(ws + 43 * MB);           // [64][256]

  prep_kernel<<<3136, 256, 0, stream>>>(x, Wq, Wk, Wv, Wo, xb, WqkT, WvT, WoT, xpart);
  qkv_kernel<<<896, 256, 0, stream>>>(xb, WqkT, WvT, bq, bk, bv, x_len, xpart,
                                      Qb, Kb, Vt, vsum);
  attn_kernel<<<1088, 256, 0, stream>>>(Qb, Kb, Vt, x_len, vsum, WoT, bo, trow, Cx);
  out_kernel<<<256, 256, 0, stream>>>(Cx, WoT, bo, x_len, trow, (float*)d_out);
}